// Round 15
// baseline (247.465 us; speedup 1.0000x reference)
//
#include <hip/hip_runtime.h>
#include <math.h>

#define NB 512
#define NATOM 32
#define NE 64
#define NK 32
#define NL1 16
#define NSG 80
#define CSTEP (5.0f / 31.0f)   // RMAX/(K-1)

// packed-table workspace byte offsets
#define PK1_OFF 0u                 // [4 t][2 hl][2 ks][64 lane] * 16B = 16 KB
#define PK2_OFF 16384u             // [5][2][2][64] * 16B = 20 KB
#define PM1_OFF 36864u             // [16 c4][3 q][64 lane] * 16B = 48 KB
#define PM2_OFF 86016u             // 48 KB
#define PMB_OFF 135168u            // [4 c4][3 q][64 lane] * 16B = 12 KB

typedef __attribute__((ext_vector_type(8)))  short s8v;      // 8 bf16 (4 VGPR)
typedef __attribute__((ext_vector_type(16))) float f16v;     // 32x32 accumulator
typedef __attribute__((ext_vector_type(4)))  unsigned u32x4;

__device__ __forceinline__ float sigm(float x) { return 1.0f / (1.0f + __expf(-x)); }

__device__ __forceinline__ short f2bf(float f) {   // RNE (prep only)
    unsigned u = __float_as_uint(f);
    unsigned r = (u + 0x7fffu + ((u >> 16) & 1u)) >> 16;
    return (short)r;
}
__device__ __forceinline__ float bf2f(short s) {
    return __uint_as_float(((unsigned)(unsigned short)s) << 16);
}

// exact truncation split of G into bf16 hi + bf16 lo (cheap, l captures h's error)
__device__ __forceinline__ void make_afrag(float rn, float mln, int hi, s8v* Ah, s8v* Al) {
#pragma unroll
    for (int ks = 0; ks < 2; ks++) {
        u32x4 uh, ul;
#pragma unroll
        for (int jj = 0; jj < 4; jj++) {
            float mu0 = (float)(ks * 16 + hi * 8 + 2 * jj) * CSTEP;
            float mu1 = (float)(ks * 16 + hi * 8 + 2 * jj + 1) * CSTEP;
            float d0 = rn - mu0, d1 = rn - mu1;
            float g0 = __expf(-10.0f * d0 * d0) * mln;
            float g1 = __expf(-10.0f * d1 * d1) * mln;
            unsigned u0 = __float_as_uint(g0), u1 = __float_as_uint(g1);
            unsigned h0 = u0 & 0xffff0000u, h1 = u1 & 0xffff0000u;
            uh[jj] = (h0 >> 16) | h1;
            float l0 = g0 - __uint_as_float(h0);
            float l1 = g1 - __uint_as_float(h1);
            ul[jj] = (__float_as_uint(l0) >> 16) | (__float_as_uint(l1) & 0xffff0000u);
        }
        Ah[ks] = __builtin_bit_cast(s8v, uh);
        Al[ks] = __builtin_bit_cast(s8v, ul);
    }
}

// ---------------- prep: pack B-fragments + mix tables ----------------
__global__ __launch_bounds__(256) void prep_kernel(
    const float* __restrict__ Wr_ss1, const float* __restrict__ Wmix_ss1,
    const float* __restrict__ Wr_sv1, const float* __restrict__ Wmix_sv1,
    const float* __restrict__ Wr_ss2, const float* __restrict__ Wmix_ss2,
    const float* __restrict__ Wr_sv2, const float* __restrict__ Wmix_sv2,
    const float* __restrict__ Wr_vv2, const float* __restrict__ Wmix_vv2,
    const float* __restrict__ Wr_vs2, const float* __restrict__ Wmix_vs2,
    char* __restrict__ ws)
{
    const int i = blockIdx.x * 256 + threadIdx.x;
    if (i < 2304) {
        int j, nt; const float* Wss; const float* Wsv; unsigned* dst;
        if (i < 1024) { j = i;        dst = (unsigned*)(ws + PK1_OFF); Wss = Wr_ss1; Wsv = Wr_sv1; nt = j >> 8; }
        else          { j = i - 1024; dst = (unsigned*)(ws + PK2_OFF); Wss = Wr_ss2; Wsv = Wr_sv2; nt = j >> 8; }
        const int r    = j & 255;
        const int hl   = r >> 7;
        const int ks   = (r >> 6) & 1;
        const int lane = r & 63;
        const int l31  = lane & 31;
        const int hi   = lane >> 5;
        const float* src; int stride;
        if (nt < 2)      { src = Wss + nt * 32 + l31;       stride = 64; }
        else if (nt < 4) { src = Wsv + (nt - 2) * 32 + l31; stride = 64; }
        else             { src = (l31 < 16) ? (Wr_vv2 + l31) : (Wr_vs2 + (l31 - 16)); stride = 16; }
        unsigned u4[4] = {0, 0, 0, 0};
#pragma unroll
        for (int jj = 0; jj < 8; jj++) {
            int k = ks * 16 + hi * 8 + jj;
            float w = src[k * stride];
            short h = f2bf(w);
            short val = hl ? f2bf(w - bf2f(h)) : h;
            u4[jj >> 1] |= ((unsigned)(unsigned short)val) << (16 * (jj & 1));
        }
        *reinterpret_cast<uint4*>(dst + (size_t)j * 4) = make_uint4(u4[0], u4[1], u4[2], u4[3]);
    } else if (i < 9216) {
        int j; const float* Wm_s; const float* Wm_v; float4* dst;
        if (i < 5376)      { j = i - 2304; dst = (float4*)(ws + PM1_OFF); Wm_s = Wmix_ss1; Wm_v = Wmix_sv1; }
        else if (i < 8448) { j = i - 5376; dst = (float4*)(ws + PM2_OFF); Wm_s = Wmix_ss2; Wm_v = Wmix_sv2; }
        else               { j = i - 8448; dst = (float4*)(ws + PMB_OFF); Wm_s = Wmix_vs2; Wm_v = Wmix_vv2; }
        const int c4   = j / 192;
        const int q    = (j / 64) % 3;
        const int lane = j & 63;
        const int d    = lane & 15;
        float4 v;
#pragma unroll
        for (int u = 0; u < 4; u++) {
            int c = c4 * 4 + u;
            float w;
            if (q == 0)      w = Wm_s[c * NSG + lane];
            else if (q == 1) w = Wm_s[c * NSG + 64 + d];
            else             w = Wm_v[c * NL1 + d];
            (&v.x)[u] = w;
        }
        dst[j] = v;
    }
}

#define PKIDX(t, hl, ks) (((((t) * 2 + (hl)) * 2 + (ks)) << 6) + lane)

// ---------------- fused both-layer kernel: one block per batch, 8 waves x 4 atoms ----------------
// VGPR ladder measured (2nd launch_bounds arg = min blocks/CU on this hipcc):
//   (512,4)->64 VGPR, 768MB spill (r7). (512,2)->128, ~110MB spill (r9). default->128+spill (r10).
// This round: (512,1) 256-VGPR budget AND accS/accV phase-split (halves acc liveness).
// Counters disambiguate: VGPR>128 => bound fired; VGPR<=128 & FETCH<5MB => split sufficed.
__global__ __launch_bounds__(512, 1) void fused_kernel(
    const int* __restrict__ Z, const float* __restrict__ geometry,
    const float* __restrict__ mask, const float* __restrict__ emb,
    const char* __restrict__ ws_ro, float* __restrict__ out)
{
    __shared__ float geo[NATOM][3];
    __shared__ float ml[NATOM];
    __shared__ int   zl[NATOM];
    __shared__ __align__(16) float rh4[NATOM][NATOM][4];  // 16 KB  [a][n]{rhat.xyz, rad}
    __shared__ float sA[NATOM][NE];                       // 8 KB   layer1 scaled input
    __shared__ float sB[NATOM][NE];                       // 8 KB   layer2 scaled input
    __shared__ float vB[NATOM][48];                       // 6 KB   layer2 scaled v input
    __shared__ __align__(16) float epi_s[8][NE];          // 2 KB   per-wave
    __shared__ __align__(16) float epi_h[8][3][NE];       // 6 KB
    __shared__ __align__(16) float epi_vv[8][3][NL1];     // 1.5 KB
    __shared__ __align__(16) float epi_vs[8][NL1];        // 0.5 KB

    const s8v*    pk1 = (const s8v*)   (ws_ro + PK1_OFF);
    const s8v*    pk2 = (const s8v*)   (ws_ro + PK2_OFF);
    const float4* pm1 = (const float4*)(ws_ro + PM1_OFF);
    const float4* pm2 = (const float4*)(ws_ro + PM2_OFF);
    const float4* pmB = (const float4*)(ws_ro + PMB_OFF);

    const int b    = blockIdx.x;
    const int tid  = threadIdx.x;
    const int wave = tid >> 6;
    const int lane = tid & 63;
    const int l31  = lane & 31;
    const int hi   = lane >> 5;
    const int d    = lane & 15;
    const int x    = lane >> 4;
    const int xe   = (x > 2) ? 0 : x;

    if (tid < 96)                 geo[tid / 3][tid % 3] = geometry[b * 96 + tid];
    if (tid >= 128 && tid < 160)  ml[tid - 128] = mask[b * NATOM + (tid - 128)];
    if (tid >= 192 && tid < 224)  zl[tid - 192] = Z[b * NATOM + (tid - 192)];
    __syncthreads();

    float msum = 0.f;
#pragma unroll
    for (int n = 0; n < NATOM; n++) msum += ml[n];
    const float scale = 1.0f / sqrtf(msum);

    // sA = emb[Z] * scale  (2048 elems / 512 thr = 4 iters)
#pragma unroll
    for (int it = 0; it < 4; it++) {
        int idx = tid + it * 512;
        sA[idx >> 6][idx & 63] = emb[zl[idx >> 6] * NE + (idx & 63)] * scale;
    }
    // all 32x32 pairs (1024 / 512 = 2 iters)
#pragma unroll
    for (int it = 0; it < 2; it++) {
        int p = tid + it * 512;
        int a = p >> 5, n = p & 31;
        float dx = geo[n][0] - geo[a][0];
        float dy = geo[n][1] - geo[a][1];
        float dz = geo[n][2] - geo[a][2];
        float rad = sqrtf(dx * dx + dy * dy + dz * dz + 1e-12f);
        float inv = 1.0f / (rad + 1e-8f);
        rh4[a][n][0] = dx * inv; rh4[a][n][1] = dy * inv;
        rh4[a][n][2] = dz * inv; rh4[a][n][3] = rad;
    }
    __syncthreads();

    // ================= layer 1: each wave does atoms a = wave*4 + ai =================
#pragma unroll 1
    for (int ai = 0; ai < 4; ai++) {
        const int a = wave * 4 + ai;
        s8v Ah[2], Al[2];
        make_afrag(rh4[a][l31][3], ml[l31], hi, Ah, Al);

#pragma unroll
        for (int p = 0; p < 2; p++) {
            const int c = p * 32 + l31;
            // ---- phase A: accS only (16 acc regs live) ----
            float ps = 0.f;
            {
                f16v accS = {};
#pragma unroll
                for (int ks = 0; ks < 2; ks++) {
                    s8v bh = pk1[PKIDX(p, 0, ks)];
                    s8v bl = pk1[PKIDX(p, 1, ks)];
                    accS = __builtin_amdgcn_mfma_f32_32x32x16_bf16(Ah[ks], bh, accS, 0, 0, 0);
                    accS = __builtin_amdgcn_mfma_f32_32x32x16_bf16(Al[ks], bh, accS, 0, 0, 0);
                    accS = __builtin_amdgcn_mfma_f32_32x32x16_bf16(Ah[ks], bl, accS, 0, 0, 0);
                }
#pragma unroll
                for (int r = 0; r < 16; r++) {
                    int n = (r & 3) + 8 * (r >> 2) + 4 * hi;   // verified C/D row map (m74/m101)
                    ps = fmaf(accS[r], sA[n][c], ps);
                }
            }
            ps += __shfl_xor(ps, 32);
            // ---- phase B: accV only ----
            float g0 = 0.f, g1 = 0.f, g2 = 0.f;
            {
                f16v accV = {};
#pragma unroll
                for (int ks = 0; ks < 2; ks++) {
                    s8v bh = pk1[PKIDX(p + 2, 0, ks)];
                    s8v bl = pk1[PKIDX(p + 2, 1, ks)];
                    accV = __builtin_amdgcn_mfma_f32_32x32x16_bf16(Ah[ks], bh, accV, 0, 0, 0);
                    accV = __builtin_amdgcn_mfma_f32_32x32x16_bf16(Al[ks], bh, accV, 0, 0, 0);
                    accV = __builtin_amdgcn_mfma_f32_32x32x16_bf16(Ah[ks], bl, accV, 0, 0, 0);
                }
#pragma unroll
                for (int r = 0; r < 16; r++) {
                    int n = (r & 3) + 8 * (r >> 2) + 4 * hi;
                    float t = accV[r] * sA[n][c];
                    float4 rr = *reinterpret_cast<const float4*>(&rh4[a][n][0]);
                    g0 = fmaf(t, rr.x, g0);
                    g1 = fmaf(t, rr.y, g1);
                    g2 = fmaf(t, rr.z, g2);
                }
            }
            g0 += __shfl_xor(g0, 32);
            g1 += __shfl_xor(g1, 32);
            g2 += __shfl_xor(g2, 32);
            if (hi == 0) {
                epi_s[wave][c]    = ps;
                epi_h[wave][0][c] = g0;
                epi_h[wave][1][c] = g1;
                epi_h[wave][2][c] = g2;
            }
        }

        // mix + activations (per-wave private epi; same-wave LDS ordering)
        float so = 0.f, so2 = 0.f, vo = 0.f;
        const float4* es4 = reinterpret_cast<const float4*>(&epi_s[wave][0]);
        const float4* eh4 = reinterpret_cast<const float4*>(&epi_h[wave][xe][0]);
#pragma unroll 4
        for (int c4 = 0; c4 < 16; c4++) {
            float4 w0 = pm1[(c4 * 3 + 0) * 64 + lane];
            float4 w1 = pm1[(c4 * 3 + 1) * 64 + lane];
            float4 w2 = pm1[(c4 * 3 + 2) * 64 + lane];
            float4 sp = es4[c4];
            float4 hp = eh4[c4];
#pragma unroll
            for (int u = 0; u < 4; u++) {
                so  = fmaf((&sp.x)[u], (&w0.x)[u], so);
                so2 = fmaf((&sp.x)[u], (&w1.x)[u], so2);
                vo  = fmaf((&hp.x)[u], (&w2.x)[u], vo);
            }
        }
        const float mls = ml[a] * scale;
        sB[a][lane] = so * sigm(so) * mls;               // scale folded for layer 2
        if (lane < 48) {
            vB[a][d * 3 + x] = vo * sigm(so2) * mls;
        }
    }
    __syncthreads();

    // ================= layer 2 =================
#pragma unroll 1
    for (int ai = 0; ai < 4; ai++) {
        const int a = wave * 4 + ai;
        s8v Ah[2], Al[2];
        make_afrag(rh4[a][l31][3], ml[l31], hi, Ah, Al);

#pragma unroll
        for (int p = 0; p < 2; p++) {
            const int c = p * 32 + l31;
            float ps = 0.f;
            {
                f16v accS = {};
#pragma unroll
                for (int ks = 0; ks < 2; ks++) {
                    s8v bh = pk2[PKIDX(p, 0, ks)];
                    s8v bl = pk2[PKIDX(p, 1, ks)];
                    accS = __builtin_amdgcn_mfma_f32_32x32x16_bf16(Ah[ks], bh, accS, 0, 0, 0);
                    accS = __builtin_amdgcn_mfma_f32_32x32x16_bf16(Al[ks], bh, accS, 0, 0, 0);
                    accS = __builtin_amdgcn_mfma_f32_32x32x16_bf16(Ah[ks], bl, accS, 0, 0, 0);
                }
#pragma unroll
                for (int r = 0; r < 16; r++) {
                    int n = (r & 3) + 8 * (r >> 2) + 4 * hi;
                    ps = fmaf(accS[r], sB[n][c], ps);
                }
            }
            ps += __shfl_xor(ps, 32);
            float g0 = 0.f, g1 = 0.f, g2 = 0.f;
            {
                f16v accV = {};
#pragma unroll
                for (int ks = 0; ks < 2; ks++) {
                    s8v bh = pk2[PKIDX(p + 2, 0, ks)];
                    s8v bl = pk2[PKIDX(p + 2, 1, ks)];
                    accV = __builtin_amdgcn_mfma_f32_32x32x16_bf16(Ah[ks], bh, accV, 0, 0, 0);
                    accV = __builtin_amdgcn_mfma_f32_32x32x16_bf16(Al[ks], bh, accV, 0, 0, 0);
                    accV = __builtin_amdgcn_mfma_f32_32x32x16_bf16(Ah[ks], bl, accV, 0, 0, 0);
                }
#pragma unroll
                for (int r = 0; r < 16; r++) {
                    int n = (r & 3) + 8 * (r >> 2) + 4 * hi;
                    float t = accV[r] * sB[n][c];
                    float4 rr = *reinterpret_cast<const float4*>(&rh4[a][n][0]);
                    g0 = fmaf(t, rr.x, g0);
                    g1 = fmaf(t, rr.y, g1);
                    g2 = fmaf(t, rr.z, g2);
                }
            }
            g0 += __shfl_xor(g0, 32);
            g1 += __shfl_xor(g1, 32);
            g2 += __shfl_xor(g2, 32);
            if (hi == 0) {
                epi_s[wave][c]    = ps;
                epi_h[wave][0][c] = g0;
                epi_h[wave][1][c] = g1;
                epi_h[wave][2][c] = g2;
            }
        }

        // tile 4: vv (l31<16) / vs (l31>=16), rv computed on the fly
        {
            f16v acc4 = {};
#pragma unroll
            for (int ks = 0; ks < 2; ks++) {
                s8v bh = pk2[PKIDX(4, 0, ks)];
                s8v bl = pk2[PKIDX(4, 1, ks)];
                acc4 = __builtin_amdgcn_mfma_f32_32x32x16_bf16(Ah[ks], bh, acc4, 0, 0, 0);
                acc4 = __builtin_amdgcn_mfma_f32_32x32x16_bf16(Al[ks], bh, acc4, 0, 0, 0);
                acc4 = __builtin_amdgcn_mfma_f32_32x32x16_bf16(Ah[ks], bl, acc4, 0, 0, 0);
            }
            const int c16 = l31 & 15;
            float hv0 = 0.f, hv1 = 0.f, hv2 = 0.f, svs = 0.f;
#pragma unroll
            for (int r = 0; r < 16; r++) {
                int n = (r & 3) + 8 * (r >> 2) + 4 * hi;
                float v0 = vB[n][c16 * 3 + 0];
                float v1 = vB[n][c16 * 3 + 1];
                float v2 = vB[n][c16 * 3 + 2];
                if (l31 < 16) {
                    hv0 = fmaf(acc4[r], v0, hv0);
                    hv1 = fmaf(acc4[r], v1, hv1);
                    hv2 = fmaf(acc4[r], v2, hv2);
                } else {
                    float4 rr = *reinterpret_cast<const float4*>(&rh4[a][n][0]);
                    float dot = fmaf(rr.x, v0, fmaf(rr.y, v1, rr.z * v2));
                    svs = fmaf(acc4[r], dot, svs);
                }
            }
            hv0 += __shfl_xor(hv0, 32);
            hv1 += __shfl_xor(hv1, 32);
            hv2 += __shfl_xor(hv2, 32);
            svs += __shfl_xor(svs, 32);
            if (hi == 0) {
                if (l31 < 16) {
                    epi_vv[wave][0][c16] = hv0;
                    epi_vv[wave][1][c16] = hv1;
                    epi_vv[wave][2][c16] = hv2;
                } else {
                    epi_vs[wave][c16] = svs;
                }
            }
        }

        // mix + activations -> global out
        float so = 0.f, so2 = 0.f, vo = 0.f;
        const float4* es4 = reinterpret_cast<const float4*>(&epi_s[wave][0]);
        const float4* eh4 = reinterpret_cast<const float4*>(&epi_h[wave][xe][0]);
#pragma unroll 4
        for (int c4 = 0; c4 < 16; c4++) {
            float4 w0 = pm2[(c4 * 3 + 0) * 64 + lane];
            float4 w1 = pm2[(c4 * 3 + 1) * 64 + lane];
            float4 w2 = pm2[(c4 * 3 + 2) * 64 + lane];
            float4 sp = es4[c4];
            float4 hp = eh4[c4];
#pragma unroll
            for (int u = 0; u < 4; u++) {
                so  = fmaf((&sp.x)[u], (&w0.x)[u], so);
                so2 = fmaf((&sp.x)[u], (&w1.x)[u], so2);
                vo  = fmaf((&hp.x)[u], (&w2.x)[u], vo);
            }
        }
        const float4* evs4 = reinterpret_cast<const float4*>(&epi_vs[wave][0]);
        const float4* evv4 = reinterpret_cast<const float4*>(&epi_vv[wave][xe][0]);
#pragma unroll
        for (int c4 = 0; c4 < 4; c4++) {
            float4 w0 = pmB[(c4 * 3 + 0) * 64 + lane];
            float4 w1 = pmB[(c4 * 3 + 1) * 64 + lane];
            float4 w2 = pmB[(c4 * 3 + 2) * 64 + lane];
            float4 vs = evs4[c4];
            float4 vv = evv4[c4];
#pragma unroll
            for (int u = 0; u < 4; u++) {
                so  = fmaf((&vs.x)[u], (&w0.x)[u], so);
                so2 = fmaf((&vs.x)[u], (&w1.x)[u], so2);
                vo  = fmaf((&vv.x)[u], (&w2.x)[u], vo);
            }
        }
        const float mla = ml[a];
        float* orow = out + (b * NATOM + a) * (NE + 3 * NL1);
        orow[lane] = so * sigm(so) * mla;
        if (lane < 48) {
            orow[64 + d * 3 + x] = vo * sigm(so2) * mla;
        }
    }
}

extern "C" void kernel_launch(void* const* d_in, const int* in_sizes, int n_in,
                              void* d_out, int out_size, void* d_ws, size_t ws_size,
                              hipStream_t stream)
{
    const int*   Z        = (const int*)  d_in[0];
    const float* geometry = (const float*)d_in[1];
    const float* mask     = (const float*)d_in[2];
    const float* emb      = (const float*)d_in[3];
    const float* Wr_ss1   = (const float*)d_in[4];
    const float* Wmix_ss1 = (const float*)d_in[5];
    const float* Wr_sv1   = (const float*)d_in[6];
    const float* Wmix_sv1 = (const float*)d_in[7];
    const float* Wr_ss2   = (const float*)d_in[8];
    const float* Wmix_ss2 = (const float*)d_in[9];
    const float* Wr_sv2   = (const float*)d_in[10];
    const float* Wmix_sv2 = (const float*)d_in[11];
    const float* Wr_vv2   = (const float*)d_in[12];
    const float* Wmix_vv2 = (const float*)d_in[13];
    const float* Wr_vs2   = (const float*)d_in[14];
    const float* Wmix_vs2 = (const float*)d_in[15];

    float* out = (float*)d_out;
    char*  ws  = (char*)d_ws;

    prep_kernel<<<36, 256, 0, stream>>>(Wr_ss1, Wmix_ss1, Wr_sv1, Wmix_sv1,
                                        Wr_ss2, Wmix_ss2, Wr_sv2, Wmix_sv2,
                                        Wr_vv2, Wmix_vv2, Wr_vs2, Wmix_vs2, ws);

    fused_kernel<<<NB, 512, 0, stream>>>(Z, geometry, mask, emb,
                                         (const char*)d_ws, out);
}

// Round 16
// 227.336 us; speedup vs baseline: 1.0885x; 1.0885x over previous
//
#include <hip/hip_runtime.h>
#include <math.h>

#define NB 512
#define NATOM 32
#define NE 64
#define NK 32
#define NL1 16
#define NSG 80
#define CSTEP (5.0f / 31.0f)   // RMAX/(K-1)

// packed-table workspace byte offsets
#define PK1_OFF 0u                 // [4 t][2 hl][2 ks][64 lane] * 16B = 16 KB
#define PK2_OFF 16384u             // [5][2][2][64] * 16B = 20 KB
#define PM1_OFF 36864u             // [16 c4][3 q][64 lane] * 16B = 48 KB
#define PM2_OFF 86016u             // 48 KB
#define PMB_OFF 135168u            // [4 c4][3 q][64 lane] * 16B = 12 KB

typedef __attribute__((ext_vector_type(8)))  short s8v;      // 8 bf16 (4 VGPR)
typedef __attribute__((ext_vector_type(16))) float f16v;     // 32x32 accumulator
typedef __attribute__((ext_vector_type(4)))  unsigned u32x4;

__device__ __forceinline__ float sigm(float x) { return 1.0f / (1.0f + __expf(-x)); }

__device__ __forceinline__ short f2bf(float f) {   // RNE (prep only)
    unsigned u = __float_as_uint(f);
    unsigned r = (u + 0x7fffu + ((u >> 16) & 1u)) >> 16;
    return (short)r;
}
__device__ __forceinline__ float bf2f(short s) {
    return __uint_as_float(((unsigned)(unsigned short)s) << 16);
}

// exact truncation split of G into bf16 hi + bf16 lo (cheap, l captures h's error)
__device__ __forceinline__ void make_afrag(float rn, float mln, int hi, s8v* Ah, s8v* Al) {
#pragma unroll
    for (int ks = 0; ks < 2; ks++) {
        u32x4 uh, ul;
#pragma unroll
        for (int jj = 0; jj < 4; jj++) {
            float mu0 = (float)(ks * 16 + hi * 8 + 2 * jj) * CSTEP;
            float mu1 = (float)(ks * 16 + hi * 8 + 2 * jj + 1) * CSTEP;
            float d0 = rn - mu0, d1 = rn - mu1;
            float g0 = __expf(-10.0f * d0 * d0) * mln;
            float g1 = __expf(-10.0f * d1 * d1) * mln;
            unsigned u0 = __float_as_uint(g0), u1 = __float_as_uint(g1);
            unsigned h0 = u0 & 0xffff0000u, h1 = u1 & 0xffff0000u;
            uh[jj] = (h0 >> 16) | h1;
            float l0 = g0 - __uint_as_float(h0);
            float l1 = g1 - __uint_as_float(h1);
            ul[jj] = (__float_as_uint(l0) >> 16) | (__float_as_uint(l1) & 0xffff0000u);
        }
        Ah[ks] = __builtin_bit_cast(s8v, uh);
        Al[ks] = __builtin_bit_cast(s8v, ul);
    }
}

// ---------------- prep: pack B-fragments + mix tables ----------------
__global__ __launch_bounds__(256) void prep_kernel(
    const float* __restrict__ Wr_ss1, const float* __restrict__ Wmix_ss1,
    const float* __restrict__ Wr_sv1, const float* __restrict__ Wmix_sv1,
    const float* __restrict__ Wr_ss2, const float* __restrict__ Wmix_ss2,
    const float* __restrict__ Wr_sv2, const float* __restrict__ Wmix_sv2,
    const float* __restrict__ Wr_vv2, const float* __restrict__ Wmix_vv2,
    const float* __restrict__ Wr_vs2, const float* __restrict__ Wmix_vs2,
    char* __restrict__ ws)
{
    const int i = blockIdx.x * 256 + threadIdx.x;
    if (i < 2304) {
        int j, nt; const float* Wss; const float* Wsv; unsigned* dst;
        if (i < 1024) { j = i;        dst = (unsigned*)(ws + PK1_OFF); Wss = Wr_ss1; Wsv = Wr_sv1; nt = j >> 8; }
        else          { j = i - 1024; dst = (unsigned*)(ws + PK2_OFF); Wss = Wr_ss2; Wsv = Wr_sv2; nt = j >> 8; }
        const int r    = j & 255;
        const int hl   = r >> 7;
        const int ks   = (r >> 6) & 1;
        const int lane = r & 63;
        const int l31  = lane & 31;
        const int hi   = lane >> 5;
        const float* src; int stride;
        if (nt < 2)      { src = Wss + nt * 32 + l31;       stride = 64; }
        else if (nt < 4) { src = Wsv + (nt - 2) * 32 + l31; stride = 64; }
        else             { src = (l31 < 16) ? (Wr_vv2 + l31) : (Wr_vs2 + (l31 - 16)); stride = 16; }
        unsigned u4[4] = {0, 0, 0, 0};
#pragma unroll
        for (int jj = 0; jj < 8; jj++) {
            int k = ks * 16 + hi * 8 + jj;
            float w = src[k * stride];
            short h = f2bf(w);
            short val = hl ? f2bf(w - bf2f(h)) : h;
            u4[jj >> 1] |= ((unsigned)(unsigned short)val) << (16 * (jj & 1));
        }
        *reinterpret_cast<uint4*>(dst + (size_t)j * 4) = make_uint4(u4[0], u4[1], u4[2], u4[3]);
    } else if (i < 9216) {
        int j; const float* Wm_s; const float* Wm_v; float4* dst;
        if (i < 5376)      { j = i - 2304; dst = (float4*)(ws + PM1_OFF); Wm_s = Wmix_ss1; Wm_v = Wmix_sv1; }
        else if (i < 8448) { j = i - 5376; dst = (float4*)(ws + PM2_OFF); Wm_s = Wmix_ss2; Wm_v = Wmix_sv2; }
        else               { j = i - 8448; dst = (float4*)(ws + PMB_OFF); Wm_s = Wmix_vs2; Wm_v = Wmix_vv2; }
        const int c4   = j / 192;
        const int q    = (j / 64) % 3;
        const int lane = j & 63;
        const int d    = lane & 15;
        float4 v;
#pragma unroll
        for (int u = 0; u < 4; u++) {
            int c = c4 * 4 + u;
            float w;
            if (q == 0)      w = Wm_s[c * NSG + lane];
            else if (q == 1) w = Wm_s[c * NSG + 64 + d];
            else             w = Wm_v[c * NL1 + d];
            (&v.x)[u] = w;
        }
        dst[j] = v;
    }
}

#define PKIDX(t, hl, ks) (((((t) * 2 + (hl)) * 2 + (ks)) << 6) + lane)

// ---------------- fused both-layer kernel: one block per batch, 4 waves x 8 atoms ----------------
// VGPR findings on this hipcc: 512-thread blocks are HARD-CAPPED at 128 VGPR (allocator spills
// ~120MB/dispatch rather than exceed it; (512,2)/(512,1)/default all identical — r9/r10/r15).
// 256-thread blocks allocate freely (r6: 76-100 VGPR, zero spill). So: 256 threads, 4 waves,
// 8 atoms/wave. Fusion requires one block per batch (layer2 reads all atoms' layer1 out via LDS).
__global__ __launch_bounds__(256) void fused_kernel(
    const int* __restrict__ Z, const float* __restrict__ geometry,
    const float* __restrict__ mask, const float* __restrict__ emb,
    const char* __restrict__ ws_ro, float* __restrict__ out)
{
    __shared__ float geo[NATOM][3];
    __shared__ float ml[NATOM];
    __shared__ int   zl[NATOM];
    __shared__ __align__(16) float rh4[NATOM][NATOM][4];  // 16 KB  [a][n]{rhat.xyz, rad}
    __shared__ float sA[NATOM][NE];                       // 8 KB   layer1 scaled input
    __shared__ float sB[NATOM][NE];                       // 8 KB   layer2 scaled input
    __shared__ float vB[NATOM][48];                       // 6 KB   layer2 scaled v input
    __shared__ __align__(16) float epi_s[4][NE];          // 1 KB   per-wave
    __shared__ __align__(16) float epi_h[4][3][NE];       // 3 KB
    __shared__ __align__(16) float epi_vv[4][3][NL1];     // 0.75 KB
    __shared__ __align__(16) float epi_vs[4][NL1];        // 0.25 KB

    const s8v*    pk1 = (const s8v*)   (ws_ro + PK1_OFF);
    const s8v*    pk2 = (const s8v*)   (ws_ro + PK2_OFF);
    const float4* pm1 = (const float4*)(ws_ro + PM1_OFF);
    const float4* pm2 = (const float4*)(ws_ro + PM2_OFF);
    const float4* pmB = (const float4*)(ws_ro + PMB_OFF);

    const int b    = blockIdx.x;
    const int tid  = threadIdx.x;
    const int wave = tid >> 6;        // 0..3
    const int lane = tid & 63;
    const int l31  = lane & 31;
    const int hi   = lane >> 5;
    const int d    = lane & 15;
    const int x    = lane >> 4;
    const int xe   = (x > 2) ? 0 : x;

    if (tid < 96)                 geo[tid / 3][tid % 3] = geometry[b * 96 + tid];
    if (tid >= 128 && tid < 160)  ml[tid - 128] = mask[b * NATOM + (tid - 128)];
    if (tid >= 192 && tid < 224)  zl[tid - 192] = Z[b * NATOM + (tid - 192)];
    __syncthreads();

    float msum = 0.f;
#pragma unroll
    for (int n = 0; n < NATOM; n++) msum += ml[n];
    const float scale = 1.0f / sqrtf(msum);

    // sA = emb[Z] * scale  (2048 elems / 256 thr = 8 iters)
#pragma unroll
    for (int it = 0; it < 8; it++) {
        int idx = tid + it * 256;
        sA[idx >> 6][idx & 63] = emb[zl[idx >> 6] * NE + (idx & 63)] * scale;
    }
    // all 32x32 pairs (1024 / 256 = 4 iters)
#pragma unroll
    for (int it = 0; it < 4; it++) {
        int p = tid + it * 256;
        int a = p >> 5, n = p & 31;
        float dx = geo[n][0] - geo[a][0];
        float dy = geo[n][1] - geo[a][1];
        float dz = geo[n][2] - geo[a][2];
        float rad = sqrtf(dx * dx + dy * dy + dz * dz + 1e-12f);
        float inv = 1.0f / (rad + 1e-8f);
        rh4[a][n][0] = dx * inv; rh4[a][n][1] = dy * inv;
        rh4[a][n][2] = dz * inv; rh4[a][n][3] = rad;
    }
    __syncthreads();

    // ================= layer 1: each wave does atoms a = wave*8 + ai =================
#pragma unroll 1
    for (int ai = 0; ai < 8; ai++) {
        const int a = wave * 8 + ai;
        s8v Ah[2], Al[2];
        make_afrag(rh4[a][l31][3], ml[l31], hi, Ah, Al);

#pragma unroll
        for (int p = 0; p < 2; p++) {
            const int c = p * 32 + l31;
            // ---- phase A: accS only ----
            float ps = 0.f;
            {
                f16v accS = {};
#pragma unroll
                for (int ks = 0; ks < 2; ks++) {
                    s8v bh = pk1[PKIDX(p, 0, ks)];
                    s8v bl = pk1[PKIDX(p, 1, ks)];
                    accS = __builtin_amdgcn_mfma_f32_32x32x16_bf16(Ah[ks], bh, accS, 0, 0, 0);
                    accS = __builtin_amdgcn_mfma_f32_32x32x16_bf16(Al[ks], bh, accS, 0, 0, 0);
                    accS = __builtin_amdgcn_mfma_f32_32x32x16_bf16(Ah[ks], bl, accS, 0, 0, 0);
                }
#pragma unroll
                for (int r = 0; r < 16; r++) {
                    int n = (r & 3) + 8 * (r >> 2) + 4 * hi;   // verified C/D row map (m74/m101)
                    ps = fmaf(accS[r], sA[n][c], ps);
                }
            }
            ps += __shfl_xor(ps, 32);
            // ---- phase B: accV only ----
            float g0 = 0.f, g1 = 0.f, g2 = 0.f;
            {
                f16v accV = {};
#pragma unroll
                for (int ks = 0; ks < 2; ks++) {
                    s8v bh = pk1[PKIDX(p + 2, 0, ks)];
                    s8v bl = pk1[PKIDX(p + 2, 1, ks)];
                    accV = __builtin_amdgcn_mfma_f32_32x32x16_bf16(Ah[ks], bh, accV, 0, 0, 0);
                    accV = __builtin_amdgcn_mfma_f32_32x32x16_bf16(Al[ks], bh, accV, 0, 0, 0);
                    accV = __builtin_amdgcn_mfma_f32_32x32x16_bf16(Ah[ks], bl, accV, 0, 0, 0);
                }
#pragma unroll
                for (int r = 0; r < 16; r++) {
                    int n = (r & 3) + 8 * (r >> 2) + 4 * hi;
                    float t = accV[r] * sA[n][c];
                    float4 rr = *reinterpret_cast<const float4*>(&rh4[a][n][0]);
                    g0 = fmaf(t, rr.x, g0);
                    g1 = fmaf(t, rr.y, g1);
                    g2 = fmaf(t, rr.z, g2);
                }
            }
            g0 += __shfl_xor(g0, 32);
            g1 += __shfl_xor(g1, 32);
            g2 += __shfl_xor(g2, 32);
            if (hi == 0) {
                epi_s[wave][c]    = ps;
                epi_h[wave][0][c] = g0;
                epi_h[wave][1][c] = g1;
                epi_h[wave][2][c] = g2;
            }
        }

        // mix + activations (per-wave private epi; same-wave LDS ordering)
        float so = 0.f, so2 = 0.f, vo = 0.f;
        const float4* es4 = reinterpret_cast<const float4*>(&epi_s[wave][0]);
        const float4* eh4 = reinterpret_cast<const float4*>(&epi_h[wave][xe][0]);
#pragma unroll 4
        for (int c4 = 0; c4 < 16; c4++) {
            float4 w0 = pm1[(c4 * 3 + 0) * 64 + lane];
            float4 w1 = pm1[(c4 * 3 + 1) * 64 + lane];
            float4 w2 = pm1[(c4 * 3 + 2) * 64 + lane];
            float4 sp = es4[c4];
            float4 hp = eh4[c4];
#pragma unroll
            for (int u = 0; u < 4; u++) {
                so  = fmaf((&sp.x)[u], (&w0.x)[u], so);
                so2 = fmaf((&sp.x)[u], (&w1.x)[u], so2);
                vo  = fmaf((&hp.x)[u], (&w2.x)[u], vo);
            }
        }
        const float mls = ml[a] * scale;
        sB[a][lane] = so * sigm(so) * mls;               // scale folded for layer 2
        if (lane < 48) {
            vB[a][d * 3 + x] = vo * sigm(so2) * mls;
        }
    }
    __syncthreads();

    // ================= layer 2 =================
#pragma unroll 1
    for (int ai = 0; ai < 8; ai++) {
        const int a = wave * 8 + ai;
        s8v Ah[2], Al[2];
        make_afrag(rh4[a][l31][3], ml[l31], hi, Ah, Al);

#pragma unroll
        for (int p = 0; p < 2; p++) {
            const int c = p * 32 + l31;
            float ps = 0.f;
            {
                f16v accS = {};
#pragma unroll
                for (int ks = 0; ks < 2; ks++) {
                    s8v bh = pk2[PKIDX(p, 0, ks)];
                    s8v bl = pk2[PKIDX(p, 1, ks)];
                    accS = __builtin_amdgcn_mfma_f32_32x32x16_bf16(Ah[ks], bh, accS, 0, 0, 0);
                    accS = __builtin_amdgcn_mfma_f32_32x32x16_bf16(Al[ks], bh, accS, 0, 0, 0);
                    accS = __builtin_amdgcn_mfma_f32_32x32x16_bf16(Ah[ks], bl, accS, 0, 0, 0);
                }
#pragma unroll
                for (int r = 0; r < 16; r++) {
                    int n = (r & 3) + 8 * (r >> 2) + 4 * hi;
                    ps = fmaf(accS[r], sB[n][c], ps);
                }
            }
            ps += __shfl_xor(ps, 32);
            float g0 = 0.f, g1 = 0.f, g2 = 0.f;
            {
                f16v accV = {};
#pragma unroll
                for (int ks = 0; ks < 2; ks++) {
                    s8v bh = pk2[PKIDX(p + 2, 0, ks)];
                    s8v bl = pk2[PKIDX(p + 2, 1, ks)];
                    accV = __builtin_amdgcn_mfma_f32_32x32x16_bf16(Ah[ks], bh, accV, 0, 0, 0);
                    accV = __builtin_amdgcn_mfma_f32_32x32x16_bf16(Al[ks], bh, accV, 0, 0, 0);
                    accV = __builtin_amdgcn_mfma_f32_32x32x16_bf16(Ah[ks], bl, accV, 0, 0, 0);
                }
#pragma unroll
                for (int r = 0; r < 16; r++) {
                    int n = (r & 3) + 8 * (r >> 2) + 4 * hi;
                    float t = accV[r] * sB[n][c];
                    float4 rr = *reinterpret_cast<const float4*>(&rh4[a][n][0]);
                    g0 = fmaf(t, rr.x, g0);
                    g1 = fmaf(t, rr.y, g1);
                    g2 = fmaf(t, rr.z, g2);
                }
            }
            g0 += __shfl_xor(g0, 32);
            g1 += __shfl_xor(g1, 32);
            g2 += __shfl_xor(g2, 32);
            if (hi == 0) {
                epi_s[wave][c]    = ps;
                epi_h[wave][0][c] = g0;
                epi_h[wave][1][c] = g1;
                epi_h[wave][2][c] = g2;
            }
        }

        // tile 4: vv (l31<16) / vs (l31>=16), rv computed on the fly
        {
            f16v acc4 = {};
#pragma unroll
            for (int ks = 0; ks < 2; ks++) {
                s8v bh = pk2[PKIDX(4, 0, ks)];
                s8v bl = pk2[PKIDX(4, 1, ks)];
                acc4 = __builtin_amdgcn_mfma_f32_32x32x16_bf16(Ah[ks], bh, acc4, 0, 0, 0);
                acc4 = __builtin_amdgcn_mfma_f32_32x32x16_bf16(Al[ks], bh, acc4, 0, 0, 0);
                acc4 = __builtin_amdgcn_mfma_f32_32x32x16_bf16(Ah[ks], bl, acc4, 0, 0, 0);
            }
            const int c16 = l31 & 15;
            float hv0 = 0.f, hv1 = 0.f, hv2 = 0.f, svs = 0.f;
#pragma unroll
            for (int r = 0; r < 16; r++) {
                int n = (r & 3) + 8 * (r >> 2) + 4 * hi;
                float v0 = vB[n][c16 * 3 + 0];
                float v1 = vB[n][c16 * 3 + 1];
                float v2 = vB[n][c16 * 3 + 2];
                if (l31 < 16) {
                    hv0 = fmaf(acc4[r], v0, hv0);
                    hv1 = fmaf(acc4[r], v1, hv1);
                    hv2 = fmaf(acc4[r], v2, hv2);
                } else {
                    float4 rr = *reinterpret_cast<const float4*>(&rh4[a][n][0]);
                    float dot = fmaf(rr.x, v0, fmaf(rr.y, v1, rr.z * v2));
                    svs = fmaf(acc4[r], dot, svs);
                }
            }
            hv0 += __shfl_xor(hv0, 32);
            hv1 += __shfl_xor(hv1, 32);
            hv2 += __shfl_xor(hv2, 32);
            svs += __shfl_xor(svs, 32);
            if (hi == 0) {
                if (l31 < 16) {
                    epi_vv[wave][0][c16] = hv0;
                    epi_vv[wave][1][c16] = hv1;
                    epi_vv[wave][2][c16] = hv2;
                } else {
                    epi_vs[wave][c16] = svs;
                }
            }
        }

        // mix + activations -> global out
        float so = 0.f, so2 = 0.f, vo = 0.f;
        const float4* es4 = reinterpret_cast<const float4*>(&epi_s[wave][0]);
        const float4* eh4 = reinterpret_cast<const float4*>(&epi_h[wave][xe][0]);
#pragma unroll 4
        for (int c4 = 0; c4 < 16; c4++) {
            float4 w0 = pm2[(c4 * 3 + 0) * 64 + lane];
            float4 w1 = pm2[(c4 * 3 + 1) * 64 + lane];
            float4 w2 = pm2[(c4 * 3 + 2) * 64 + lane];
            float4 sp = es4[c4];
            float4 hp = eh4[c4];
#pragma unroll
            for (int u = 0; u < 4; u++) {
                so  = fmaf((&sp.x)[u], (&w0.x)[u], so);
                so2 = fmaf((&sp.x)[u], (&w1.x)[u], so2);
                vo  = fmaf((&hp.x)[u], (&w2.x)[u], vo);
            }
        }
        const float4* evs4 = reinterpret_cast<const float4*>(&epi_vs[wave][0]);
        const float4* evv4 = reinterpret_cast<const float4*>(&epi_vv[wave][xe][0]);
#pragma unroll
        for (int c4 = 0; c4 < 4; c4++) {
            float4 w0 = pmB[(c4 * 3 + 0) * 64 + lane];
            float4 w1 = pmB[(c4 * 3 + 1) * 64 + lane];
            float4 w2 = pmB[(c4 * 3 + 2) * 64 + lane];
            float4 vs = evs4[c4];
            float4 vv = evv4[c4];
#pragma unroll
            for (int u = 0; u < 4; u++) {
                so  = fmaf((&vs.x)[u], (&w0.x)[u], so);
                so2 = fmaf((&vs.x)[u], (&w1.x)[u], so2);
                vo  = fmaf((&vv.x)[u], (&w2.x)[u], vo);
            }
        }
        const float mla = ml[a];
        float* orow = out + (b * NATOM + a) * (NE + 3 * NL1);
        orow[lane] = so * sigm(so) * mla;
        if (lane < 48) {
            orow[64 + d * 3 + x] = vo * sigm(so2) * mla;
        }
    }
}

extern "C" void kernel_launch(void* const* d_in, const int* in_sizes, int n_in,
                              void* d_out, int out_size, void* d_ws, size_t ws_size,
                              hipStream_t stream)
{
    const int*   Z        = (const int*)  d_in[0];
    const float* geometry = (const float*)d_in[1];
    const float* mask     = (const float*)d_in[2];
    const float* emb      = (const float*)d_in[3];
    const float* Wr_ss1   = (const float*)d_in[4];
    const float* Wmix_ss1 = (const float*)d_in[5];
    const float* Wr_sv1   = (const float*)d_in[6];
    const float* Wmix_sv1 = (const float*)d_in[7];
    const float* Wr_ss2   = (const float*)d_in[8];
    const float* Wmix_ss2 = (const float*)d_in[9];
    const float* Wr_sv2   = (const float*)d_in[10];
    const float* Wmix_sv2 = (const float*)d_in[11];
    const float* Wr_vv2   = (const float*)d_in[12];
    const float* Wmix_vv2 = (const float*)d_in[13];
    const float* Wr_vs2   = (const float*)d_in[14];
    const float* Wmix_vs2 = (const float*)d_in[15];

    float* out = (float*)d_out;
    char*  ws  = (char*)d_ws;

    prep_kernel<<<36, 256, 0, stream>>>(Wr_ss1, Wmix_ss1, Wr_sv1, Wmix_sv1,
                                        Wr_ss2, Wmix_ss2, Wr_sv2, Wmix_sv2,
                                        Wr_vv2, Wmix_vv2, Wr_vs2, Wmix_vs2, ws);

    fused_kernel<<<NB, 256, 0, stream>>>(Z, geometry, mask, emb,
                                         (const char*)d_ws, out);
}